// Round 7
// baseline (390.631 us; speedup 1.0000x reference)
//
#include <hip/hip_runtime.h>
#include <hip/hip_bf16.h>

// BasicAttention: B=4, S=2048, E=1024, QD=VD=1024, fp32 in/out.
// Pipeline (all bf16 MFMA, fp32 accum):
//   1. cast_x:   x fp32 [8192,1024] -> xb bf16
//   2. cast_wt:  Wq/Wk/Wv fp32 [E,D] -> Wt bf16 [D,E] (transposed -> B^T GEMMs)
//   3. gemm<0> x2: Q/K projections -> bf16 [8192,1024]
//   4. gemm<1>:    V projection, TRANSPOSED store Vt[b][d][s]
//   5. gemm<2>:    S = Q@K^T*(1/1024), mask==0 -> -1e30, fp32
//   6. softmax_rows: P = softmax(S) -> bf16
//   7. gemm<3>:    out = P@Vt^T -> fp32
//
// R6->R7: restructured K-loop (the documented path past the 2-barrier stall):
//  - BK 64->32, TRIPLE-buffered LDS (3 x 16KB = 48KB) -> 3 blocks/CU
//    (VGPR 88+64acc allows 3 waves/SIMD; 64KB LDS was the binder at 2).
//  - Hand-rolled barriers: s_waitcnt vmcnt(4) lgkmcnt(0) + s_barrier
//    (vmcnt(0) only on the last iter). 2-deep prefetch: tile i+2 issued at
//    iter i, so each tile has ~2 compute phases to land instead of being
//    force-drained by __syncthreads' vmcnt(0).
//  - Col-chunk-major staging (lane: row=l&15, chunk=l>>4): ds_read_b128
//    becomes one contiguous 1KB wave read -> conflict-free, XOR swizzle gone.
//  Accumulation order along K unchanged -> bit-identical output.
//
// Workspace (MB): xb@0(16) Wt@16(6) Qb@22(16) Kb@38(16) Vt@54(16) Sf@70(64);
// Pb aliases @22(32). Total 134 MB.

typedef __bf16 bf16x8 __attribute__((ext_vector_type(8)));
typedef __bf16 bf16x4 __attribute__((ext_vector_type(4)));
typedef float f32x4 __attribute__((ext_vector_type(4)));

#define BM 128
#define BN 128
#define BK 32

// async global->LDS, 16B per lane; LDS dest = wave-uniform base + lane*16
__device__ inline void glds16(const __bf16* g, __bf16* l) {
    __builtin_amdgcn_global_load_lds(
        (const __attribute__((address_space(1))) unsigned int*)g,
        (__attribute__((address_space(3))) unsigned int*)l,
        16, 0, 0);
}

// C = A @ B^T. A: [M,K] bf16 row-major. B: [N,K] bf16 row-major (B^T input).
template <int EPI>
__global__ __launch_bounds__(256) void gemm_bt(
    const __bf16* __restrict__ A, const __bf16* __restrict__ B,
    float* __restrict__ Cf, __bf16* __restrict__ Cb,
    const float* __restrict__ bias, const int* __restrict__ mask,
    int M, int N, int K, float scale,
    long sA, long sB, long sC, long sM)
{
    A += (long)blockIdx.z * sA;
    B += (long)blockIdx.z * sB;
    if (EPI >= 2) Cf += (long)blockIdx.z * sC;
    if (EPI == 2) mask += (long)blockIdx.z * sM;

    __shared__ __align__(16) char smraw[49152];   // 3 x (A 8K + B 8K)
    float* smC = (float*)smraw;                   // [32][132] epilogue view

    const int t = threadIdx.x;
    const int w = t >> 6;          // wave 0..3
    const int l = t & 63;          // lane
    const int row0 = blockIdx.x * BM;
    const int col0 = blockIdx.y * BN;
    const int wm = (w >> 1) * 64;  // wave's 64x64 quadrant
    const int wn = (w & 1) * 64;

    // staging (col-chunk-major): lane l covers row l&15 of its 16-row group,
    // 16B k-chunk l>>4. LDS element (g,p,r,j) = g*512 + p*128 + r*8 + j
    // holds A[row=g*16+r][k=p*8+j] -> wave ds_read_b128 is 1KB contiguous.
    const int lr16 = l & 15;
    const int lch  = (l >> 4) * 8;

    // fragment indices (A: m=lane&15, k=(lane>>4)*8+j — m91-verified)
    const int lm = l & 15;
    const int g16 = l >> 4;

    f32x4 acc[4][4];
#pragma unroll
    for (int i = 0; i < 4; i++)
#pragma unroll
        for (int j = 0; j < 4; j++) acc[i][j] = (f32x4){0.f, 0.f, 0.f, 0.f};

    auto stage = [&](int buf, int kt) {
        __bf16* sA = (__bf16*)(smraw + buf * 16384);
        __bf16* sB = sA + 4096;
#pragma unroll
        for (int j = 0; j < 2; j++) {
            const int g = j * 4 + w;               // 16-row group 0..7
            const int r = g * 16 + lr16;
            glds16(A + (size_t)(row0 + r) * K + kt + lch, &sA[g * 512]);
            glds16(B + (size_t)(col0 + r) * K + kt + lch, &sB[g * 512]);
        }
    };

    const int n = K / BK;
    stage(0, 0);
    stage(1, BK);

    int cur = 0, nxt = 2;
    for (int i = 0; i < n; i++) {
        if (i < n - 1) {
            // tile i landed iff my outstanding loads <= 4 (only tile i+1 newer)
            asm volatile("s_waitcnt vmcnt(4) lgkmcnt(0)\n\ts_barrier" ::: "memory");
        } else {
            asm volatile("s_waitcnt vmcnt(0) lgkmcnt(0)\n\ts_barrier" ::: "memory");
        }
        if (i + 2 < n) {
            stage(nxt, (i + 2) * BK);
        }

        const __bf16* sA = (const __bf16*)(smraw + cur * 16384);
        const __bf16* sB = sA + 4096;
        bf16x8 af[4], bg[4];
#pragma unroll
        for (int mt = 0; mt < 4; mt++)
            af[mt] = *(const bf16x8*)&sA[(wm + mt * 16) * 32 + g16 * 128 + lm * 8];
#pragma unroll
        for (int nt = 0; nt < 4; nt++)
            bg[nt] = *(const bf16x8*)&sB[(wn + nt * 16) * 32 + g16 * 128 + lm * 8];
#pragma unroll
        for (int mt = 0; mt < 4; mt++)
#pragma unroll
            for (int nt = 0; nt < 4; nt++)
                acc[mt][nt] = __builtin_amdgcn_mfma_f32_16x16x32_bf16(
                    af[mt], bg[nt], acc[mt][nt], 0, 0, 0);

        cur = cur == 2 ? 0 : cur + 1;
        nxt = nxt == 2 ? 0 : nxt + 1;
    }
    __syncthreads();             // all reads done before smC aliasing

    // ---- epilogue: stage C through LDS, emit coalesced global IO ----
    // C/D layout col=lane&15, row=(lane>>4)*4+i  [m91-verified]
    const int rl = (l >> 4) * 4;
    float breg[4];
    if (EPI <= 1) {
#pragma unroll
        for (int nt = 0; nt < 4; nt++) breg[nt] = bias[col0 + wn + nt * 16 + lm];
    }
#pragma unroll
    for (int mt = 0; mt < 4; mt++) {
        // write phase: 32 rows (two 16-row groups) x 128 cols into smC[32][132]
#pragma unroll
        for (int nt = 0; nt < 4; nt++)
#pragma unroll
            for (int i = 0; i < 4; i++) {
                const int lr = (w >> 1) * 16 + rl + i;   // 0..31
                const int c  = wn + nt * 16 + lm;        // 0..127
                float v = acc[mt][nt][i];
                if (EPI <= 1) v += breg[nt];
                if (EPI == 2) v *= scale;
                smC[lr * 132 + c] = v;
            }
        __syncthreads();

        if (EPI == 1) {
            // transposed store: Vt[batch][d][s], 64B segments per d
#pragma unroll
            for (int k = 0; k < 4; k++) {
                const int d  = (t >> 3) + 32 * k;        // 0..127
                const int sc = (t & 7) * 4;              // 0..28 (stays in 16-group)
                const int gr = row0 + mt * 16 + (sc & 15) + (sc >> 4) * 64;
                bf16x4 o;
#pragma unroll
                for (int j = 0; j < 4; j++) o[j] = (__bf16)smC[(sc + j) * 132 + d];
                *(bf16x4*)&Cb[(size_t)(gr >> 11) * ((size_t)N * 2048)
                              + (size_t)(col0 + d) * 2048 + (gr & 2047)] = o;
            }
        } else {
#pragma unroll
            for (int k = 0; k < 4; k++) {
                const int lr = (t >> 5) + 8 * k;         // 0..31
                const int c4 = (t & 31) * 4;             // 0..124
                const int gr = row0 + mt * 16 + (lr & 15) + (lr >> 4) * 64;
                const float4 v = *(const float4*)&smC[lr * 132 + c4];
                if (EPI == 0) {
                    bf16x4 o = {(__bf16)v.x, (__bf16)v.y, (__bf16)v.z, (__bf16)v.w};
                    *(bf16x4*)&Cb[(size_t)gr * N + col0 + c4] = o;
                } else if (EPI == 2) {
                    const int4 mk = *(const int4*)&mask[(size_t)gr * N + col0 + c4];
                    float4 o;
                    o.x = mk.x ? v.x : -1e30f;
                    o.y = mk.y ? v.y : -1e30f;
                    o.z = mk.z ? v.z : -1e30f;
                    o.w = mk.w ? v.w : -1e30f;
                    *(float4*)&Cf[(size_t)gr * N + col0 + c4] = o;
                } else {
                    *(float4*)&Cf[(size_t)gr * N + col0 + c4] = v;
                }
            }
        }
        __syncthreads();
    }
}

__global__ __launch_bounds__(256) void cast_x(const float* __restrict__ X, __bf16* __restrict__ Y) {
    const size_t i = (size_t)blockIdx.x * 256 + threadIdx.x;
    const float4* X4 = (const float4*)X;
    const float4 a = X4[i * 2], b = X4[i * 2 + 1];
    bf16x8 o = {(__bf16)a.x, (__bf16)a.y, (__bf16)a.z, (__bf16)a.w,
                (__bf16)b.x, (__bf16)b.y, (__bf16)b.z, (__bf16)b.w};
    ((bf16x8*)Y)[i] = o;
}

// W [E=1024, D=1024] fp32 -> Wt [D, E] bf16, z selects q/k/v
__global__ void cast_wt(const float* __restrict__ Wq, const float* __restrict__ Wk,
                        const float* __restrict__ Wv, __bf16* __restrict__ Wt) {
    const float* W = blockIdx.z == 0 ? Wq : (blockIdx.z == 1 ? Wk : Wv);
    __bf16* O = Wt + (size_t)blockIdx.z * 1024 * 1024;
    __shared__ float tile[32][33];
    const int tx = threadIdx.x, ty = threadIdx.y;
    const int d0 = blockIdx.x * 32, e0 = blockIdx.y * 32;
#pragma unroll
    for (int j = 0; j < 32; j += 8)
        tile[ty + j][tx] = W[(size_t)(e0 + ty + j) * 1024 + d0 + tx];
    __syncthreads();
#pragma unroll
    for (int j = 0; j < 32; j += 8)
        O[(size_t)(d0 + ty + j) * 1024 + e0 + tx] = (__bf16)tile[tx][ty + j];
}

// one block per row of 2048; S fp32 [8192][2048] -> P bf16
__global__ __launch_bounds__(256) void softmax_rows(const float* __restrict__ S,
                                                    __bf16* __restrict__ P) {
    const size_t row = blockIdx.x;
    const float4* s4 = (const float4*)(S + row * 2048);
    const int t = threadIdx.x;
    const int w = t >> 6, l = t & 63;
    const float4 a = s4[t * 2], b = s4[t * 2 + 1];
    float v[8] = {a.x, a.y, a.z, a.w, b.x, b.y, b.z, b.w};
    float m = v[0];
#pragma unroll
    for (int i = 1; i < 8; i++) m = fmaxf(m, v[i]);
#pragma unroll
    for (int off = 32; off; off >>= 1) m = fmaxf(m, __shfl_xor(m, off, 64));
    __shared__ float rm[4], rs[4];
    if (l == 0) rm[w] = m;
    __syncthreads();
    m = fmaxf(fmaxf(rm[0], rm[1]), fmaxf(rm[2], rm[3]));
    float e[8], sum = 0.f;
#pragma unroll
    for (int i = 0; i < 8; i++) { e[i] = __expf(v[i] - m); sum += e[i]; }
#pragma unroll
    for (int off = 32; off; off >>= 1) sum += __shfl_xor(sum, off, 64);
    if (l == 0) rs[w] = sum;
    __syncthreads();
    const float inv = 1.f / (rs[0] + rs[1] + rs[2] + rs[3]);
    bf16x8 o;
#pragma unroll
    for (int i = 0; i < 8; i++) o[i] = (__bf16)(e[i] * inv);
    ((bf16x8*)(P + row * 2048))[t] = o;
}

extern "C" void kernel_launch(void* const* d_in, const int* in_sizes, int n_in,
                              void* d_out, int out_size, void* d_ws, size_t ws_size,
                              hipStream_t stream) {
    const float* x  = (const float*)d_in[0];
    const int* mask = (const int*)d_in[1];
    const float* Wq = (const float*)d_in[2];
    const float* bq = (const float*)d_in[3];
    const float* Wk = (const float*)d_in[4];
    const float* bk = (const float*)d_in[5];
    const float* Wv = (const float*)d_in[6];
    const float* bv = (const float*)d_in[7];
    float* out = (float*)d_out;

    char* ws = (char*)d_ws;
    __bf16* xb = (__bf16*)(ws);                        // 16 MB
    __bf16* Wt = (__bf16*)(ws + (16ull << 20));        //  6 MB
    __bf16* Qb = (__bf16*)(ws + (22ull << 20));        // 16 MB
    __bf16* Kb = (__bf16*)(ws + (38ull << 20));        // 16 MB
    __bf16* Vt = (__bf16*)(ws + (54ull << 20));        // 16 MB
    float*  Sf = (float*) (ws + (70ull << 20));        // 64 MB
    __bf16* Pb = (__bf16*)(ws + (22ull << 20));        // 32 MB, aliases Qb+Kb (dead)

    cast_x<<<4096, 256, 0, stream>>>(x, xb);
    cast_wt<<<dim3(32, 32, 3), dim3(32, 8), 0, stream>>>(Wq, Wk, Wv, Wt);

    // projections: M=8192, N=1024, K=1024
    gemm_bt<0><<<dim3(64, 8, 1), 256, 0, stream>>>(xb, Wt, nullptr, Qb, bq, nullptr,
                                                   8192, 1024, 1024, 1.f, 0, 0, 0, 0);
    gemm_bt<0><<<dim3(64, 8, 1), 256, 0, stream>>>(xb, Wt + (1u << 20), nullptr, Kb, bk, nullptr,
                                                   8192, 1024, 1024, 1.f, 0, 0, 0, 0);
    gemm_bt<1><<<dim3(64, 8, 1), 256, 0, stream>>>(xb, Wt + (2u << 20), nullptr, Vt, bv, nullptr,
                                                   8192, 1024, 1024, 1.f, 0, 0, 0, 0);

    // scores: per batch, M=N=2048, K=1024, scale 1/QD, mask applied
    gemm_bt<2><<<dim3(16, 16, 4), 256, 0, stream>>>(Qb, Kb, Sf, nullptr, nullptr, mask,
                                                    2048, 2048, 1024, 1.0f / 1024.0f,
                                                    2048L * 1024, 2048L * 1024,
                                                    2048L * 2048, 2048L * 2048);

    softmax_rows<<<8192, 256, 0, stream>>>(Sf, Pb);

    // out = P @ V: per batch, M=2048, N=1024, K=2048
    gemm_bt<3><<<dim3(16, 8, 4), 256, 0, stream>>>(Pb, Vt, out, nullptr, nullptr, nullptr,
                                                   2048, 1024, 2048, 1.f,
                                                   2048L * 2048, 1024L * 2048,
                                                   2048L * 1024, 0);
}

// Round 8
// 314.273 us; speedup vs baseline: 1.2430x; 1.2430x over previous
//
#include <hip/hip_runtime.h>
#include <hip/hip_bf16.h>

// BasicAttention: B=4, S=2048, E=1024, QD=VD=1024, fp32 in/out.
// Pipeline (all bf16 MFMA, fp32 accum):
//   1. cast_x:   x fp32 [8192,1024] -> xb bf16
//   2. cast_wt:  Wq/Wk/Wv fp32 [E,D] -> Wt bf16 [D,E] (transposed -> B^T GEMMs)
//   3. gemm<0> x2: Q/K projections -> bf16 [8192,1024]
//   4. gemm<1>:    V projection, TRANSPOSED store Vt[b][d][s]
//   5. gemm<2>:    S = Q@K^T*(1/1024), mask==0 -> -1e30, fp32
//   6. softmax_rows: P = softmax(S) -> bf16
//   7. gemm<3>:    out = P@Vt^T -> fp32
//
// R7->R8: (a) REVERT K-loop to R6 shape (BK=64, double-buffered 2x32KB,
// single __syncthreads per iter) — R7's BK=32 + asm-vmcnt pipeline regressed
// 64->87us (2x barriers, half MFMA/barrier). (b) NEW: XCD-aware block
// swizzle (SWZ template). Evidence: staged LDS bytes = 512MB/dispatch vs
// FETCH 106MB -> staging is L2/LLC-served; natural dispatch scatters each
// XCD over 2 batches' K panels (8MB >> 4MB L2) -> LLC-BW-bound (~8TB/s).
//   SWZ=1 (scores): XCD p&7 gets a 4x4 block rect = 512 Q-rows x 1024
//     K-cols (1MB+2MB < 4MB L2).
//   SWZ=2 (PV): by = p&7 fixed per XCD -> Vt panel L2-resident, P streams.
//
// Workspace (MB): xb@0(16) Wt@16(6) Qb@22(16) Kb@38(16) Vt@54(16) Sf@70(64);
// Pb aliases @22(32). Total 134 MB.

typedef __bf16 bf16x8 __attribute__((ext_vector_type(8)));
typedef __bf16 bf16x4 __attribute__((ext_vector_type(4)));
typedef float f32x4 __attribute__((ext_vector_type(4)));

#define BM 128
#define BN 128
#define BK 64

// async global->LDS, 16B per lane; LDS dest = wave-uniform base + lane*16
__device__ inline void glds16(const __bf16* g, __bf16* l) {
    __builtin_amdgcn_global_load_lds(
        (const __attribute__((address_space(1))) unsigned int*)g,
        (__attribute__((address_space(3))) unsigned int*)l,
        16, 0, 0);
}

// C = A @ B^T. A: [M,K] bf16 row-major. B: [N,K] bf16 row-major (B^T input).
template <int EPI, int SWZ>
__global__ __launch_bounds__(256) void gemm_bt(
    const __bf16* __restrict__ A, const __bf16* __restrict__ B,
    float* __restrict__ Cf, __bf16* __restrict__ Cb,
    const float* __restrict__ bias, const int* __restrict__ mask,
    int M, int N, int K, float scale,
    long sA, long sB, long sC, long sM)
{
    A += (long)blockIdx.z * sA;
    B += (long)blockIdx.z * sB;
    if (EPI >= 2) Cf += (long)blockIdx.z * sC;
    if (EPI == 2) mask += (long)blockIdx.z * sM;

    // XCD-aware tile assignment (HW round-robins blocks to XCDs by flat id%8)
    int bx, by;
    if (SWZ == 1) {            // 16x16 grid via 1-D p: XCD x8 owns 4x4 rect
        const int p = blockIdx.x, x8 = p & 7, s = p >> 3;
        bx = (x8 & 3) * 4 + (s & 3);
        by = (x8 >> 2) * 8 + (s >> 2);
    } else if (SWZ == 2) {     // 16x8 grid via 1-D p: by fixed per XCD
        bx = blockIdx.x >> 3;
        by = blockIdx.x & 7;
    } else {
        bx = blockIdx.x;
        by = blockIdx.y;
    }

    __shared__ __align__(16) char smraw[65536];   // 2 x (A 16K + B 16K)
    float* smC = (float*)smraw;                   // [32][132] epilogue view

    const int t = threadIdx.x;
    const int w = t >> 6;          // wave 0..3
    const int l = t & 63;          // lane
    const int row0 = bx * BM;
    const int col0 = by * BN;
    const int wm = (w >> 1) * 64;  // wave's 64x64 quadrant
    const int wn = (w & 1) * 64;

    // staging: chunk = i*4+w covers rows [chunk*8, chunk*8+8), 64 k-elems each
    const int srow = l >> 3;                       // 0..7 row within chunk
    const int skel = (((l & 7) ^ srow) & 7) * 8;   // SWIZZLED global chunk offset

    // fragment indices (A: m=lane&15, k=(lane>>4)*8+j — m91-verified)
    const int lm = l & 15;
    const int g16 = l >> 4;        // 16-lane group 0..3
    const int sx = lm & 7;         // row swizzle key

    f32x4 acc[4][4];
#pragma unroll
    for (int i = 0; i < 4; i++)
#pragma unroll
        for (int j = 0; j < 4; j++) acc[i][j] = (f32x4){0.f, 0.f, 0.f, 0.f};

    auto stage = [&](int buf, int kt) {
        __bf16* sA = (__bf16*)(smraw + buf * 32768);
        __bf16* sB = sA + BM * BK;
#pragma unroll
        for (int i = 0; i < 4; i++) {
            const int chunk = i * 4 + w;
            const int r = chunk * 8 + srow;
            glds16(A + (size_t)(row0 + r) * K + kt + skel, &sA[chunk * 512]);
            glds16(B + (size_t)(col0 + r) * K + kt + skel, &sB[chunk * 512]);
        }
    };

    stage(0, 0);                 // prologue
    int cur = 0;
    for (int kt = 0; kt < K; kt += BK) {
        __syncthreads();         // buf[cur] loads landed during prev compute
        if (kt + BK < K) stage(cur ^ 1, kt + BK);

        const __bf16* sA = (const __bf16*)(smraw + cur * 32768);
        const __bf16* sB = sA + BM * BK;
#pragma unroll
        for (int ks = 0; ks < 2; ks++) {
            bf16x8 af[4], bg[4];
            const int p = ((ks * 4 + g16) ^ sx) * 8;   // swizzled position
#pragma unroll
            for (int mt = 0; mt < 4; mt++)
                af[mt] = *(const bf16x8*)&sA[(wm + mt * 16 + lm) * BK + p];
#pragma unroll
            for (int nt = 0; nt < 4; nt++)
                bg[nt] = *(const bf16x8*)&sB[(wn + nt * 16 + lm) * BK + p];
#pragma unroll
            for (int mt = 0; mt < 4; mt++)
#pragma unroll
                for (int nt = 0; nt < 4; nt++)
                    acc[mt][nt] = __builtin_amdgcn_mfma_f32_16x16x32_bf16(
                        af[mt], bg[nt], acc[mt][nt], 0, 0, 0);
        }
        cur ^= 1;
    }
    __syncthreads();             // all reads done before smC aliasing

    // ---- epilogue: stage C through LDS, emit coalesced global IO ----
    // C/D layout col=lane&15, row=(lane>>4)*4+i  [m91-verified]
    const int rl = (l >> 4) * 4;
    float breg[4];
    if (EPI <= 1) {
#pragma unroll
        for (int nt = 0; nt < 4; nt++) breg[nt] = bias[col0 + wn + nt * 16 + lm];
    }
#pragma unroll
    for (int mt = 0; mt < 4; mt++) {
        // write phase: 32 rows (two 16-row groups) x 128 cols into smC[32][132]
#pragma unroll
        for (int nt = 0; nt < 4; nt++)
#pragma unroll
            for (int i = 0; i < 4; i++) {
                const int lr = (w >> 1) * 16 + rl + i;   // 0..31
                const int c  = wn + nt * 16 + lm;        // 0..127
                float v = acc[mt][nt][i];
                if (EPI <= 1) v += breg[nt];
                if (EPI == 2) v *= scale;
                smC[lr * 132 + c] = v;
            }
        __syncthreads();

        if (EPI == 1) {
            // transposed store: Vt[batch][d][s], 64B segments per d
#pragma unroll
            for (int k = 0; k < 4; k++) {
                const int d  = (t >> 3) + 32 * k;        // 0..127
                const int sc = (t & 7) * 4;              // 0..28 (stays in 16-group)
                const int gr = row0 + mt * 16 + (sc & 15) + (sc >> 4) * 64;
                bf16x4 o;
#pragma unroll
                for (int j = 0; j < 4; j++) o[j] = (__bf16)smC[(sc + j) * 132 + d];
                *(bf16x4*)&Cb[(size_t)(gr >> 11) * ((size_t)N * 2048)
                              + (size_t)(col0 + d) * 2048 + (gr & 2047)] = o;
            }
        } else {
#pragma unroll
            for (int k = 0; k < 4; k++) {
                const int lr = (t >> 5) + 8 * k;         // 0..31
                const int c4 = (t & 31) * 4;             // 0..124
                const int gr = row0 + mt * 16 + (lr & 15) + (lr >> 4) * 64;
                const float4 v = *(const float4*)&smC[lr * 132 + c4];
                if (EPI == 0) {
                    bf16x4 o = {(__bf16)v.x, (__bf16)v.y, (__bf16)v.z, (__bf16)v.w};
                    *(bf16x4*)&Cb[(size_t)gr * N + col0 + c4] = o;
                } else if (EPI == 2) {
                    const int4 mk = *(const int4*)&mask[(size_t)gr * N + col0 + c4];
                    float4 o;
                    o.x = mk.x ? v.x : -1e30f;
                    o.y = mk.y ? v.y : -1e30f;
                    o.z = mk.z ? v.z : -1e30f;
                    o.w = mk.w ? v.w : -1e30f;
                    *(float4*)&Cf[(size_t)gr * N + col0 + c4] = o;
                } else {
                    *(float4*)&Cf[(size_t)gr * N + col0 + c4] = v;
                }
            }
        }
        __syncthreads();
    }
}

__global__ __launch_bounds__(256) void cast_x(const float* __restrict__ X, __bf16* __restrict__ Y) {
    const size_t i = (size_t)blockIdx.x * 256 + threadIdx.x;
    const float4* X4 = (const float4*)X;
    const float4 a = X4[i * 2], b = X4[i * 2 + 1];
    bf16x8 o = {(__bf16)a.x, (__bf16)a.y, (__bf16)a.z, (__bf16)a.w,
                (__bf16)b.x, (__bf16)b.y, (__bf16)b.z, (__bf16)b.w};
    ((bf16x8*)Y)[i] = o;
}

// W [E=1024, D=1024] fp32 -> Wt [D, E] bf16, z selects q/k/v
__global__ void cast_wt(const float* __restrict__ Wq, const float* __restrict__ Wk,
                        const float* __restrict__ Wv, __bf16* __restrict__ Wt) {
    const float* W = blockIdx.z == 0 ? Wq : (blockIdx.z == 1 ? Wk : Wv);
    __bf16* O = Wt + (size_t)blockIdx.z * 1024 * 1024;
    __shared__ float tile[32][33];
    const int tx = threadIdx.x, ty = threadIdx.y;
    const int d0 = blockIdx.x * 32, e0 = blockIdx.y * 32;
#pragma unroll
    for (int j = 0; j < 32; j += 8)
        tile[ty + j][tx] = W[(size_t)(e0 + ty + j) * 1024 + d0 + tx];
    __syncthreads();
#pragma unroll
    for (int j = 0; j < 32; j += 8)
        O[(size_t)(d0 + ty + j) * 1024 + e0 + tx] = (__bf16)tile[tx][ty + j];
}

// one block per row of 2048; S fp32 [8192][2048] -> P bf16
__global__ __launch_bounds__(256) void softmax_rows(const float* __restrict__ S,
                                                    __bf16* __restrict__ P) {
    const size_t row = blockIdx.x;
    const float4* s4 = (const float4*)(S + row * 2048);
    const int t = threadIdx.x;
    const int w = t >> 6, l = t & 63;
    const float4 a = s4[t * 2], b = s4[t * 2 + 1];
    float v[8] = {a.x, a.y, a.z, a.w, b.x, b.y, b.z, b.w};
    float m = v[0];
#pragma unroll
    for (int i = 1; i < 8; i++) m = fmaxf(m, v[i]);
#pragma unroll
    for (int off = 32; off; off >>= 1) m = fmaxf(m, __shfl_xor(m, off, 64));
    __shared__ float rm[4], rs[4];
    if (l == 0) rm[w] = m;
    __syncthreads();
    m = fmaxf(fmaxf(rm[0], rm[1]), fmaxf(rm[2], rm[3]));
    float e[8], sum = 0.f;
#pragma unroll
    for (int i = 0; i < 8; i++) { e[i] = __expf(v[i] - m); sum += e[i]; }
#pragma unroll
    for (int off = 32; off; off >>= 1) sum += __shfl_xor(sum, off, 64);
    if (l == 0) rs[w] = sum;
    __syncthreads();
    const float inv = 1.f / (rs[0] + rs[1] + rs[2] + rs[3]);
    bf16x8 o;
#pragma unroll
    for (int i = 0; i < 8; i++) o[i] = (__bf16)(e[i] * inv);
    ((bf16x8*)(P + row * 2048))[t] = o;
}

extern "C" void kernel_launch(void* const* d_in, const int* in_sizes, int n_in,
                              void* d_out, int out_size, void* d_ws, size_t ws_size,
                              hipStream_t stream) {
    const float* x  = (const float*)d_in[0];
    const int* mask = (const int*)d_in[1];
    const float* Wq = (const float*)d_in[2];
    const float* bq = (const float*)d_in[3];
    const float* Wk = (const float*)d_in[4];
    const float* bk = (const float*)d_in[5];
    const float* Wv = (const float*)d_in[6];
    const float* bv = (const float*)d_in[7];
    float* out = (float*)d_out;

    char* ws = (char*)d_ws;
    __bf16* xb = (__bf16*)(ws);                        // 16 MB
    __bf16* Wt = (__bf16*)(ws + (16ull << 20));        //  6 MB
    __bf16* Qb = (__bf16*)(ws + (22ull << 20));        // 16 MB
    __bf16* Kb = (__bf16*)(ws + (38ull << 20));        // 16 MB
    __bf16* Vt = (__bf16*)(ws + (54ull << 20));        // 16 MB
    float*  Sf = (float*) (ws + (70ull << 20));        // 64 MB
    __bf16* Pb = (__bf16*)(ws + (22ull << 20));        // 32 MB, aliases Qb+Kb (dead)

    cast_x<<<4096, 256, 0, stream>>>(x, xb);
    cast_wt<<<dim3(32, 32, 3), dim3(32, 8), 0, stream>>>(Wq, Wk, Wv, Wt);

    // projections: M=8192, N=1024, K=1024 (natural mapping, ws fits L2)
    gemm_bt<0, 0><<<dim3(64, 8, 1), 256, 0, stream>>>(xb, Wt, nullptr, Qb, bq, nullptr,
                                                      8192, 1024, 1024, 1.f, 0, 0, 0, 0);
    gemm_bt<0, 0><<<dim3(64, 8, 1), 256, 0, stream>>>(xb, Wt + (1u << 20), nullptr, Kb, bk, nullptr,
                                                      8192, 1024, 1024, 1.f, 0, 0, 0, 0);
    gemm_bt<1, 0><<<dim3(64, 8, 1), 256, 0, stream>>>(xb, Wt + (2u << 20), nullptr, Vt, bv, nullptr,
                                                      8192, 1024, 1024, 1.f, 0, 0, 0, 0);

    // scores: per batch, M=N=2048, K=1024; SWZ=1 rect clustering per XCD
    gemm_bt<2, 1><<<dim3(256, 1, 4), 256, 0, stream>>>(Qb, Kb, Sf, nullptr, nullptr, mask,
                                                       2048, 2048, 1024, 1.0f / 1024.0f,
                                                       2048L * 1024, 2048L * 1024,
                                                       2048L * 2048, 2048L * 2048);

    softmax_rows<<<8192, 256, 0, stream>>>(Sf, Pb);

    // out = P @ V: per batch, M=2048, N=1024, K=2048; SWZ=2 (col fixed/XCD)
    gemm_bt<3, 2><<<dim3(128, 1, 4), 256, 0, stream>>>(Pb, Vt, out, nullptr, nullptr, nullptr,
                                                       2048, 1024, 2048, 1.f,
                                                       2048L * 2048, 1024L * 2048,
                                                       2048L * 1024, 0);
}

// Round 9
// 302.433 us; speedup vs baseline: 1.2916x; 1.0391x over previous
//
#include <hip/hip_runtime.h>
#include <hip/hip_bf16.h>

// BasicAttention: B=4, S=2048, E=1024, QD=VD=1024, fp32 in/out.
// Pipeline (all bf16 MFMA, fp32 accum):
//   1. cast_x:   x fp32 [8192,1024] -> xb bf16
//   2. cast_wt:  Wq/Wk/Wv fp32 [E,D] -> Wt bf16 [D,E] (transposed -> B^T GEMMs)
//   3. gemm<0> x2: Q/K projections -> bf16 [8192,1024]
//   4. gemm<1>:    V projection, TRANSPOSED store Vt[b][d][s]
//   5. gemm<4>:    S = Q@K^T*(1/1024) -> bf16 (NO mask here)
//   6. softmax_rows: P = softmax(mask ? S : -1e30) -> bf16  (mask read HERE, once)
//   7. gemm<3>:    out = P@Vt^T -> fp32
//
// R8->R9: (a) revert XCD swizzles — SWZ=1 cut FETCH 106->83MB but cost +10us
// (L2 contention, fetch BW was not binding); back to R6 natural mapping.
// (b) Traffic diet on scores+softmax: Sf stored as bf16 (logits are tiny,
// std~0.01 -> bf16 abs err ~1e-4, invisible vs absmax 4.9e-4) and mask
// moved out of the GEMM epilogue into softmax. Scores traffic:
// 106MB fetch + 64MB write -> ~40MB + 32MB. Mask read exactly once.
//
// Workspace (MB): xb@0(16) Wt@16(6) Qb@22(16) Kb@38(16) Vt@54(16) Sf@70(32,bf16);
// Pb aliases @22(32). Total 102 MB.

typedef __bf16 bf16x8 __attribute__((ext_vector_type(8)));
typedef __bf16 bf16x4 __attribute__((ext_vector_type(4)));
typedef float f32x4 __attribute__((ext_vector_type(4)));

#define BM 128
#define BN 128
#define BK 64

// async global->LDS, 16B per lane; LDS dest = wave-uniform base + lane*16
__device__ inline void glds16(const __bf16* g, __bf16* l) {
    __builtin_amdgcn_global_load_lds(
        (const __attribute__((address_space(1))) unsigned int*)g,
        (__attribute__((address_space(3))) unsigned int*)l,
        16, 0, 0);
}

// C = A @ B^T. A: [M,K] bf16 row-major. B: [N,K] bf16 row-major (B^T input).
// EPI 0: Cb = bf16(acc + bias)      EPI 1: V transposed bf16 store (+bias)
// EPI 3: Cf = acc (fp32)            EPI 4: Cb = bf16(acc * scale)
template <int EPI>
__global__ __launch_bounds__(256) void gemm_bt(
    const __bf16* __restrict__ A, const __bf16* __restrict__ B,
    float* __restrict__ Cf, __bf16* __restrict__ Cb,
    const float* __restrict__ bias,
    int M, int N, int K, float scale,
    long sA, long sB, long sC)
{
    A += (long)blockIdx.z * sA;
    B += (long)blockIdx.z * sB;
    if (EPI == 3) Cf += (long)blockIdx.z * sC;
    if (EPI == 4) Cb += (long)blockIdx.z * sC;

    __shared__ __align__(16) char smraw[65536];   // 2 x (A 16K + B 16K)
    float* smC = (float*)smraw;                   // [32][132] epilogue view

    const int t = threadIdx.x;
    const int w = t >> 6;          // wave 0..3
    const int l = t & 63;          // lane
    const int row0 = blockIdx.x * BM;
    const int col0 = blockIdx.y * BN;
    const int wm = (w >> 1) * 64;  // wave's 64x64 quadrant
    const int wn = (w & 1) * 64;

    // staging: chunk = i*4+w covers rows [chunk*8, chunk*8+8), 64 k-elems each
    const int srow = l >> 3;                       // 0..7 row within chunk
    const int skel = (((l & 7) ^ srow) & 7) * 8;   // SWIZZLED global chunk offset

    // fragment indices (A: m=lane&15, k=(lane>>4)*8+j — m91-verified)
    const int lm = l & 15;
    const int g16 = l >> 4;        // 16-lane group 0..3
    const int sx = lm & 7;         // row swizzle key

    f32x4 acc[4][4];
#pragma unroll
    for (int i = 0; i < 4; i++)
#pragma unroll
        for (int j = 0; j < 4; j++) acc[i][j] = (f32x4){0.f, 0.f, 0.f, 0.f};

    auto stage = [&](int buf, int kt) {
        __bf16* sA = (__bf16*)(smraw + buf * 32768);
        __bf16* sB = sA + BM * BK;
#pragma unroll
        for (int i = 0; i < 4; i++) {
            const int chunk = i * 4 + w;
            const int r = chunk * 8 + srow;
            glds16(A + (size_t)(row0 + r) * K + kt + skel, &sA[chunk * 512]);
            glds16(B + (size_t)(col0 + r) * K + kt + skel, &sB[chunk * 512]);
        }
    };

    stage(0, 0);                 // prologue
    int cur = 0;
    for (int kt = 0; kt < K; kt += BK) {
        __syncthreads();         // buf[cur] loads landed during prev compute
        if (kt + BK < K) stage(cur ^ 1, kt + BK);

        const __bf16* sA = (const __bf16*)(smraw + cur * 32768);
        const __bf16* sB = sA + BM * BK;
#pragma unroll
        for (int ks = 0; ks < 2; ks++) {
            bf16x8 af[4], bg[4];
            const int p = ((ks * 4 + g16) ^ sx) * 8;   // swizzled position
#pragma unroll
            for (int mt = 0; mt < 4; mt++)
                af[mt] = *(const bf16x8*)&sA[(wm + mt * 16 + lm) * BK + p];
#pragma unroll
            for (int nt = 0; nt < 4; nt++)
                bg[nt] = *(const bf16x8*)&sB[(wn + nt * 16 + lm) * BK + p];
#pragma unroll
            for (int mt = 0; mt < 4; mt++)
#pragma unroll
                for (int nt = 0; nt < 4; nt++)
                    acc[mt][nt] = __builtin_amdgcn_mfma_f32_16x16x32_bf16(
                        af[mt], bg[nt], acc[mt][nt], 0, 0, 0);
        }
        cur ^= 1;
    }
    __syncthreads();             // all reads done before smC aliasing

    // ---- epilogue: stage C through LDS, emit coalesced global IO ----
    // C/D layout col=lane&15, row=(lane>>4)*4+i  [m91-verified]
    const int rl = (l >> 4) * 4;
    float breg[4];
    if (EPI <= 1) {
#pragma unroll
        for (int nt = 0; nt < 4; nt++) breg[nt] = bias[col0 + wn + nt * 16 + lm];
    }
#pragma unroll
    for (int mt = 0; mt < 4; mt++) {
        // write phase: 32 rows (two 16-row groups) x 128 cols into smC[32][132]
#pragma unroll
        for (int nt = 0; nt < 4; nt++)
#pragma unroll
            for (int i = 0; i < 4; i++) {
                const int lr = (w >> 1) * 16 + rl + i;   // 0..31
                const int c  = wn + nt * 16 + lm;        // 0..127
                float v = acc[mt][nt][i];
                if (EPI <= 1) v += breg[nt];
                if (EPI == 4) v *= scale;
                smC[lr * 132 + c] = v;
            }
        __syncthreads();

        if (EPI == 1) {
            // transposed store: Vt[batch][d][s], 64B segments per d
#pragma unroll
            for (int k = 0; k < 4; k++) {
                const int d  = (t >> 3) + 32 * k;        // 0..127
                const int sc = (t & 7) * 4;              // 0..28 (stays in 16-group)
                const int gr = row0 + mt * 16 + (sc & 15) + (sc >> 4) * 64;
                bf16x4 o;
#pragma unroll
                for (int j = 0; j < 4; j++) o[j] = (__bf16)smC[(sc + j) * 132 + d];
                *(bf16x4*)&Cb[(size_t)(gr >> 11) * ((size_t)N * 2048)
                              + (size_t)(col0 + d) * 2048 + (gr & 2047)] = o;
            }
        } else {
#pragma unroll
            for (int k = 0; k < 4; k++) {
                const int lr = (t >> 5) + 8 * k;         // 0..31
                const int c4 = (t & 31) * 4;             // 0..124
                const int gr = row0 + mt * 16 + (lr & 15) + (lr >> 4) * 64;
                const float4 v = *(const float4*)&smC[lr * 132 + c4];
                if (EPI == 0 || EPI == 4) {
                    bf16x4 o = {(__bf16)v.x, (__bf16)v.y, (__bf16)v.z, (__bf16)v.w};
                    *(bf16x4*)&Cb[(size_t)gr * N + col0 + c4] = o;
                } else {
                    *(float4*)&Cf[(size_t)gr * N + col0 + c4] = v;
                }
            }
        }
        __syncthreads();
    }
}

__global__ __launch_bounds__(256) void cast_x(const float* __restrict__ X, __bf16* __restrict__ Y) {
    const size_t i = (size_t)blockIdx.x * 256 + threadIdx.x;
    const float4* X4 = (const float4*)X;
    const float4 a = X4[i * 2], b = X4[i * 2 + 1];
    bf16x8 o = {(__bf16)a.x, (__bf16)a.y, (__bf16)a.z, (__bf16)a.w,
                (__bf16)b.x, (__bf16)b.y, (__bf16)b.z, (__bf16)b.w};
    ((bf16x8*)Y)[i] = o;
}

// W [E=1024, D=1024] fp32 -> Wt [D, E] bf16, z selects q/k/v
__global__ void cast_wt(const float* __restrict__ Wq, const float* __restrict__ Wk,
                        const float* __restrict__ Wv, __bf16* __restrict__ Wt) {
    const float* W = blockIdx.z == 0 ? Wq : (blockIdx.z == 1 ? Wk : Wv);
    __bf16* O = Wt + (size_t)blockIdx.z * 1024 * 1024;
    __shared__ float tile[32][33];
    const int tx = threadIdx.x, ty = threadIdx.y;
    const int d0 = blockIdx.x * 32, e0 = blockIdx.y * 32;
#pragma unroll
    for (int j = 0; j < 32; j += 8)
        tile[ty + j][tx] = W[(size_t)(e0 + ty + j) * 1024 + d0 + tx];
    __syncthreads();
#pragma unroll
    for (int j = 0; j < 32; j += 8)
        O[(size_t)(d0 + ty + j) * 1024 + e0 + tx] = (__bf16)tile[tx][ty + j];
}

// one block per row of 2048; S bf16 + mask int32 -> P bf16
// masked-out -> -1e30 (finite sentinel: all-masked row gives uniform, and
// that case has probability ~2^-2048 anyway; matches prior passing behavior)
__global__ __launch_bounds__(256) void softmax_rows(const __bf16* __restrict__ S,
                                                    const int* __restrict__ mask,
                                                    __bf16* __restrict__ P) {
    const size_t row = blockIdx.x;
    const int t = threadIdx.x;
    const int w = t >> 6, l = t & 63;
    const bf16x8 s8 = ((const bf16x8*)(S + row * 2048))[t];
    const int4 mk0 = ((const int4*)(mask + row * 2048))[t * 2];
    const int4 mk1 = ((const int4*)(mask + row * 2048))[t * 2 + 1];
    float v[8];
    v[0] = mk0.x ? (float)s8[0] : -1e30f;
    v[1] = mk0.y ? (float)s8[1] : -1e30f;
    v[2] = mk0.z ? (float)s8[2] : -1e30f;
    v[3] = mk0.w ? (float)s8[3] : -1e30f;
    v[4] = mk1.x ? (float)s8[4] : -1e30f;
    v[5] = mk1.y ? (float)s8[5] : -1e30f;
    v[6] = mk1.z ? (float)s8[6] : -1e30f;
    v[7] = mk1.w ? (float)s8[7] : -1e30f;
    float m = v[0];
#pragma unroll
    for (int i = 1; i < 8; i++) m = fmaxf(m, v[i]);
#pragma unroll
    for (int off = 32; off; off >>= 1) m = fmaxf(m, __shfl_xor(m, off, 64));
    __shared__ float rm[4], rs[4];
    if (l == 0) rm[w] = m;
    __syncthreads();
    m = fmaxf(fmaxf(rm[0], rm[1]), fmaxf(rm[2], rm[3]));
    float e[8], sum = 0.f;
#pragma unroll
    for (int i = 0; i < 8; i++) { e[i] = __expf(v[i] - m); sum += e[i]; }
#pragma unroll
    for (int off = 32; off; off >>= 1) sum += __shfl_xor(sum, off, 64);
    if (l == 0) rs[w] = sum;
    __syncthreads();
    const float inv = 1.f / (rs[0] + rs[1] + rs[2] + rs[3]);
    bf16x8 o;
#pragma unroll
    for (int i = 0; i < 8; i++) o[i] = (__bf16)(e[i] * inv);
    ((bf16x8*)(P + row * 2048))[t] = o;
}

extern "C" void kernel_launch(void* const* d_in, const int* in_sizes, int n_in,
                              void* d_out, int out_size, void* d_ws, size_t ws_size,
                              hipStream_t stream) {
    const float* x  = (const float*)d_in[0];
    const int* mask = (const int*)d_in[1];
    const float* Wq = (const float*)d_in[2];
    const float* bq = (const float*)d_in[3];
    const float* Wk = (const float*)d_in[4];
    const float* bk = (const float*)d_in[5];
    const float* Wv = (const float*)d_in[6];
    const float* bv = (const float*)d_in[7];
    float* out = (float*)d_out;

    char* ws = (char*)d_ws;
    __bf16* xb = (__bf16*)(ws);                        // 16 MB
    __bf16* Wt = (__bf16*)(ws + (16ull << 20));        //  6 MB
    __bf16* Qb = (__bf16*)(ws + (22ull << 20));        // 16 MB
    __bf16* Kb = (__bf16*)(ws + (38ull << 20));        // 16 MB
    __bf16* Vt = (__bf16*)(ws + (54ull << 20));        // 16 MB
    __bf16* Sf = (__bf16*)(ws + (70ull << 20));        // 32 MB (bf16 now)
    __bf16* Pb = (__bf16*)(ws + (22ull << 20));        // 32 MB, aliases Qb+Kb (dead)

    cast_x<<<4096, 256, 0, stream>>>(x, xb);
    cast_wt<<<dim3(32, 32, 3), dim3(32, 8), 0, stream>>>(Wq, Wk, Wv, Wt);

    // projections: M=8192, N=1024, K=1024
    gemm_bt<0><<<dim3(64, 8, 1), 256, 0, stream>>>(xb, Wt, nullptr, Qb, bq,
                                                   8192, 1024, 1024, 1.f, 0, 0, 0);
    gemm_bt<0><<<dim3(64, 8, 1), 256, 0, stream>>>(xb, Wt + (1u << 20), nullptr, Kb, bk,
                                                   8192, 1024, 1024, 1.f, 0, 0, 0);
    gemm_bt<1><<<dim3(64, 8, 1), 256, 0, stream>>>(xb, Wt + (2u << 20), nullptr, Vt, bv,
                                                   8192, 1024, 1024, 1.f, 0, 0, 0);

    // scores: per batch, M=N=2048, K=1024 -> bf16 Sf, scale folded, mask-free
    gemm_bt<4><<<dim3(16, 16, 4), 256, 0, stream>>>(Qb, Kb, nullptr, Sf, nullptr,
                                                    2048, 2048, 1024, 1.0f / 1024.0f,
                                                    2048L * 1024, 2048L * 1024,
                                                    2048L * 2048);

    softmax_rows<<<8192, 256, 0, stream>>>(Sf, mask, Pb);

    // out = P @ V: per batch, M=2048, N=1024, K=2048
    gemm_bt<3><<<dim3(16, 8, 4), 256, 0, stream>>>(Pb, Vt, out, nullptr, nullptr,
                                                   2048, 1024, 2048, 1.f,
                                                   2048L * 2048, 1024L * 2048,
                                                   2048L * 1024);
}